// Round 2
// baseline (110.012 us; speedup 1.0000x reference)
//
#include <hip/hip_runtime.h>

#define N_ROWS 16384
#define R_REL  64
#define IN_D   128
#define OUT_D  128
#define BM     32
#define TPB_PRE 1024
#define TPB_G   256
#define NSLAB   16
#define HCOPIES 4
#define HSTRIDE 65   // 65-int stride => each copy shifted by 1 bank

__device__ __forceinline__ float f4c(const float4& v, int i) {
  return i == 0 ? v.x : i == 1 ? v.y : i == 2 ? v.z : v.w;
}

// ---------------------------------------------------------------------------
// k_pre: one block. Reads relations once (cached in LDS as u16), histograms
// into 4 bank-shifted LDS copies, wave-scans the 64 summed counts, writes
// offsets[65], then scatters row indices grouped-by-relation into row_idx[N].
// ---------------------------------------------------------------------------
__global__ __launch_bounds__(TPB_PRE, 1) void k_pre(const int* __restrict__ rel,
                                                    int* __restrict__ offsets,
                                                    int* __restrict__ row_idx) {
  __shared__ unsigned short srel[N_ROWS];     // 32 KB
  __shared__ int hist[HCOPIES * HSTRIDE];     // banked histogram copies
  __shared__ int cnt[R_REL];                  // scatter cursors
  __shared__ int pref[R_REL + 1];
  const int t = threadIdx.x;
  const int hc = (t >> 6) & (HCOPIES - 1);    // wave id mod 4 picks a copy

  for (int i = t; i < HCOPIES * HSTRIDE; i += TPB_PRE) hist[i] = 0;
  __syncthreads();

  // 16384 ints = 4096 int4; 1024 threads x 4 int4 each, coalesced.
  int* h = &hist[hc * HSTRIDE];
  #pragma unroll
  for (int b = 0; b < N_ROWS / (TPB_PRE * 4); ++b) {
    const int idx = b * TPB_PRE + t;
    const int4 v = ((const int4*)rel)[idx];
    const int base = idx * 4;
    srel[base + 0] = (unsigned short)v.x;
    srel[base + 1] = (unsigned short)v.y;
    srel[base + 2] = (unsigned short)v.z;
    srel[base + 3] = (unsigned short)v.w;
    atomicAdd(&h[v.x], 1);
    atomicAdd(&h[v.y], 1);
    atomicAdd(&h[v.z], 1);
    atomicAdd(&h[v.w], 1);
  }
  __syncthreads();

  // exclusive prefix over 64 summed counts, wave 0 via shfl_up scan
  if (t < R_REL) {
    int v = 0;
    #pragma unroll
    for (int c = 0; c < HCOPIES; ++c) v += hist[c * HSTRIDE + t];
    #pragma unroll
    for (int d = 1; d < R_REL; d <<= 1) {
      const int u = __shfl_up(v, d, 64);
      if (t >= d) v += u;
    }
    pref[t + 1] = v;          // inclusive -> pref[t+1]
    if (t == 0) pref[0] = 0;
  }
  __syncthreads();

  if (t < R_REL) cnt[t] = pref[t];            // cnt becomes the running cursor
  if (t < R_REL + 1) offsets[t] = pref[t];
  __syncthreads();

  for (int i = t; i < N_ROWS; i += TPB_PRE) {
    const int r = srel[i];
    const int pos = atomicAdd(&cnt[r], 1);
    row_idx[pos] = i;
  }
}

// ---------------------------------------------------------------------------
// k_gemm: block = (relation, row-tile of BM=32 gathered rows) x 128 outs.
// 256 threads: tx in [0,16) owns 8 contiguous outs; ty in [0,16) owns 2 rows.
// x tile staged in LDS with 16B-chunk XOR swizzle (write hits the 512B/128B
// bank floor; read is 16-lane broadcast + 4 distinct bank-groups -> free);
// w streamed from L1/L2 (hot: 64KB/relation, 4MB total), 8-out register reuse.
// ---------------------------------------------------------------------------
__global__ __launch_bounds__(TPB_G, 4) void k_gemm(const float* __restrict__ x,
                                                   const float* __restrict__ w,
                                                   const float* __restrict__ bias,
                                                   const int* __restrict__ offsets,
                                                   const int* __restrict__ row_idx,
                                                   float* __restrict__ out) {
  __shared__ __align__(16) float xs[BM * IN_D];   // 16 KB, swizzled 16B chunks
  const int r = blockIdx.y;
  const int beg = offsets[r];
  const int cnt = offsets[r + 1] - beg;
  const int t  = threadIdx.x;
  const int tx = t & 15;
  const int ty = t >> 4;

  for (int tile = blockIdx.x; tile * BM < cnt; tile += NSLAB) {
    const int m0 = beg + tile * BM;
    const int rows = min(BM, cnt - tile * BM);

    // ---- stage x tile: 32 rows x 128 f32. thread t: row = t&31, q = t>>5 ----
    {
      const int row = t & 31;
      const int q = t >> 5;                      // 0..7, 4 chunks (16 floats)
      if (row < rows) {
        const int g = row_idx[m0 + row];
        const float4* src = (const float4*)(x + (size_t)g * IN_D) + q * 4;
        float4* dst = (float4*)xs + row * 32;
        const int sw = row & 7;
        #pragma unroll
        for (int j = 0; j < 4; ++j) {
          dst[(q * 4 + j) ^ sw] = src[j];
        }
      }
    }
    __syncthreads();

    // ---- K loop: 32 chunks of 4 k ----
    float acc[2][8];
    #pragma unroll
    for (int i = 0; i < 2; ++i)
      #pragma unroll
      for (int j = 0; j < 8; ++j) acc[i][j] = 0.f;

    const float* wp = w + (size_t)r * (IN_D * OUT_D) + tx * 8;
    const int m_a = ty * 2, m_b = ty * 2 + 1;
    const float4* xsa = (const float4*)xs + m_a * 32;
    const float4* xsb = (const float4*)xs + m_b * 32;
    const int swa = m_a & 7, swb = m_b & 7;

    #pragma unroll 4
    for (int kc = 0; kc < 32; ++kc) {
      float4 wv[4][2];
      #pragma unroll
      for (int kk = 0; kk < 4; ++kk) {
        const float4* p = (const float4*)(wp + (size_t)(kc * 4 + kk) * OUT_D);
        wv[kk][0] = p[0];
        wv[kk][1] = p[1];
      }
      const float4 xva = xsa[kc ^ swa];
      const float4 xvb = xsb[kc ^ swb];
      #pragma unroll
      for (int kk = 0; kk < 4; ++kk) {
        const float xa = f4c(xva, kk);
        const float xb = f4c(xvb, kk);
        #pragma unroll
        for (int h = 0; h < 2; ++h) {
          const float4 wq = wv[kk][h];
          acc[0][h * 4 + 0] += xa * wq.x;
          acc[0][h * 4 + 1] += xa * wq.y;
          acc[0][h * 4 + 2] += xa * wq.z;
          acc[0][h * 4 + 3] += xa * wq.w;
          acc[1][h * 4 + 0] += xb * wq.x;
          acc[1][h * 4 + 1] += xb * wq.y;
          acc[1][h * 4 + 2] += xb * wq.z;
          acc[1][h * 4 + 3] += xb * wq.w;
        }
      }
    }

    // ---- epilogue: + bias, store 8 contiguous outs per row ----
    const float4* bp = (const float4*)(bias + (size_t)r * OUT_D + tx * 8);
    const float4 b0 = bp[0], b1 = bp[1];
    #pragma unroll
    for (int i = 0; i < 2; ++i) {
      const int m = ty * 2 + i;
      if (m < rows) {
        const int g = row_idx[m0 + m];
        float4* op = (float4*)(out + (size_t)g * OUT_D + tx * 8);
        float4 o0, o1;
        o0.x = acc[i][0] + b0.x; o0.y = acc[i][1] + b0.y;
        o0.z = acc[i][2] + b0.z; o0.w = acc[i][3] + b0.w;
        o1.x = acc[i][4] + b1.x; o1.y = acc[i][5] + b1.y;
        o1.z = acc[i][6] + b1.z; o1.w = acc[i][7] + b1.w;
        op[0] = o0;
        op[1] = o1;
      }
    }
    __syncthreads();
  }
}

extern "C" void kernel_launch(void* const* d_in, const int* in_sizes, int n_in,
                              void* d_out, int out_size, void* d_ws, size_t ws_size,
                              hipStream_t stream) {
  const float* x    = (const float*)d_in[0];
  const int*   rel  = (const int*)d_in[1];
  const float* w    = (const float*)d_in[2];
  const float* bias = (const float*)d_in[3];
  float* out = (float*)d_out;

  // ws layout: offsets[65] at +0 (padded to 128 ints), row_idx[16384] after.
  int* offsets = (int*)d_ws;
  int* row_idx = (int*)d_ws + 128;

  k_pre<<<1, TPB_PRE, 0, stream>>>(rel, offsets, row_idx);
  k_gemm<<<dim3(NSLAB, R_REL), TPB_G, 0, stream>>>(x, w, bias, offsets, row_idx, out);
}

// Round 8
// 106.248 us; speedup vs baseline: 1.0354x; 1.0354x over previous
//
#include <hip/hip_runtime.h>

#define N_ROWS 16384
#define R_REL  64
#define IN_D   128
#define OUT_D  128
#define BM     64          // rows per tile (= wavefront size: lane == row)
#define NS     4           // row-slab blocks per (relation, col-half)
#define TPB_G  256

__device__ __forceinline__ float f4c(const float4& v, int i) {
  return i == 0 ? v.x : i == 1 ? v.y : i == 2 ? v.z : v.w;
}

// ---------------------------------------------------------------------------
// k_pre v2 (unchanged, audited): 64 blocks, one per relation, NO atomics.
// Block r: offset = #{i : rel[i] < r} (block reduce), then stable compaction
// of matching rows via shfl prefix scan, 1024 rows/chunk.
// ---------------------------------------------------------------------------
__global__ __launch_bounds__(256, 4) void k_pre(const int* __restrict__ rel,
                                                int* __restrict__ offsets,
                                                int* __restrict__ row_idx) {
  const int r = blockIdx.x;
  const int t = threadIdx.x;
  const int wid = t >> 6, lane = t & 63;
  __shared__ int wsum[4];
  __shared__ int sbase;
  const int4* rel4 = (const int4*)rel;

  // ---- pass 1: exclusive offset = count(rel < r) ----
  int lt = 0;
  for (int i = t; i < N_ROWS / 4; i += 256) {
    const int4 v = rel4[i];
    lt += (v.x < r) + (v.y < r) + (v.z < r) + (v.w < r);
  }
  #pragma unroll
  for (int d = 32; d >= 1; d >>= 1) lt += __shfl_down(lt, d, 64);
  if (lane == 0) wsum[wid] = lt;
  __syncthreads();
  if (t == 0) {
    const int o = wsum[0] + wsum[1] + wsum[2] + wsum[3];
    sbase = o;
    offsets[r] = o;
    if (r == R_REL - 1) offsets[R_REL] = N_ROWS;
  }
  __syncthreads();
  int base = sbase;

  // ---- pass 2: stable compact matching rows, 16 chunks x 1024 rows ----
  for (int c = 0; c < 16; ++c) {
    const int i4 = c * 256 + t;
    const int4 v = rel4[i4];
    const int m0 = (v.x == r), m1 = (v.y == r), m2 = (v.z == r), m3 = (v.w == r);
    const int cnt_t = m0 + m1 + m2 + m3;
    int incl = cnt_t;
    #pragma unroll
    for (int d = 1; d < 64; d <<= 1) {
      const int u = __shfl_up(incl, d, 64);
      if (lane >= d) incl += u;
    }
    if (lane == 63) wsum[wid] = incl;
    __syncthreads();
    int wbase = 0;
    for (int ww = 0; ww < wid; ++ww) wbase += wsum[ww];
    int pos = base + wbase + incl - cnt_t;
    const int row0 = i4 * 4;
    if (m0) row_idx[pos++] = row0;
    if (m1) row_idx[pos++] = row0 + 1;
    if (m2) row_idx[pos++] = row0 + 2;
    if (m3) row_idx[pos++] = row0 + 3;
    base += wsum[0] + wsum[1] + wsum[2] + wsum[3];
    __syncthreads();
  }
}

// ---------------------------------------------------------------------------
// k_gemm v3: scalar-pipe w. Block = (relation r, col-half of 64, row-slab).
// 4 waves; wave wq covers ALL 64 tile rows (lane == row) x 16 cols
// (c0 + wq*16). w addresses depend only on (r, k, wq) -> wave-uniform ->
// s_load_dwordx16 on the scalar pipe (no VALU/vector-LDS cost). Per kc(4k)
// per wave: 1 ds_read_b128 (x, swizzled, hits 1024B/8clk floor) +
// 4 s_load_dwordx16 (w) + 64 v_fmac (SGPR*VGPR). No w LDS at all ->
// 32 KB LDS/block, high occupancy. VALU floor 3.4 us is the target.
// ---------------------------------------------------------------------------
__global__ __launch_bounds__(TPB_G, 4) void k_gemm(const float* __restrict__ x,
                                                   const float* __restrict__ w,
                                                   const float* __restrict__ bias,
                                                   const int* __restrict__ offsets,
                                                   const int* __restrict__ row_idx,
                                                   float* __restrict__ out) {
  __shared__ __align__(16) float xs[BM * IN_D];    // 32 KB, swizzled 16B slots
  const int r = blockIdx.y;
  const int c0 = blockIdx.z * 64;
  const int beg = offsets[r];
  const int cnt = offsets[r + 1] - beg;
  if (cnt == 0) return;
  const int t = threadIdx.x;
  // readfirstlane makes the wave id PROVABLY uniform -> w/bias loads scalarize
  const int wq = __builtin_amdgcn_readfirstlane(t >> 6);
  const int lane = t & 63;
  const int cw = c0 + wq * 16;                     // this wave's 16 cols

  // bias slice for this wave's cols: uniform -> scalar load, lives in SGPRs
  float bs[16];
  #pragma unroll
  for (int j = 0; j < 16; ++j) bs[j] = bias[(size_t)r * OUT_D + cw + j];

  const float* wbase = w + (size_t)r * (IN_D * OUT_D) + cw;  // w[r][k][cw..+16)

  for (int tile = blockIdx.x; tile * BM < cnt; tile += NS) {
    const int m0 = beg + tile * BM;
    const int rows = min(BM, cnt - tile * BM);

    // ---- stage x tile: 64 rows x 128 f32; thread: row=t&63, q=t>>6 ----
    {
      const int row = t & 63;
      const int q = t >> 6;                // 0..3, 8 float4 each
      if (row < rows) {
        const int g = row_idx[m0 + row];
        const float4* src = (const float4*)(x + (size_t)g * IN_D) + q * 8;
        float4* dst = (float4*)xs + row * 32;
        const int sw = row & 7;
        #pragma unroll
        for (int j = 0; j < 8; ++j) dst[(q * 8 + j) ^ sw] = src[j];
      }
    }
    __syncthreads();

    // ---- K loop: lane == row; 16 accumulators (this wave's 16 cols) ----
    float acc[16];
    #pragma unroll
    for (int j = 0; j < 16; ++j) acc[j] = 0.f;

    const float4* xp = (const float4*)xs + lane * 32;
    const int sw = lane & 7;

    #pragma unroll 4
    for (int kc = 0; kc < 32; ++kc) {
      const float4 xv = xp[kc ^ sw];             // 4 k-values for my row
      #pragma unroll
      for (int kk = 0; kk < 4; ++kk) {
        const float* wk = wbase + (size_t)(kc * 4 + kk) * OUT_D;  // uniform
        const float xk = f4c(xv, kk);
        #pragma unroll
        for (int j = 0; j < 16; ++j) acc[j] = fmaf(wk[j], xk, acc[j]);
      }
    }

    // ---- epilogue: + bias, store my row's 16 cols (64B, aligned) ----
    if (lane < rows) {
      const int g = row_idx[m0 + lane];
      float* op = out + (size_t)g * OUT_D + cw;
      float4 o;
      o.x = acc[0] + bs[0];  o.y = acc[1] + bs[1];
      o.z = acc[2] + bs[2];  o.w = acc[3] + bs[3];
      *(float4*)(op + 0) = o;
      o.x = acc[4] + bs[4];  o.y = acc[5] + bs[5];
      o.z = acc[6] + bs[6];  o.w = acc[7] + bs[7];
      *(float4*)(op + 4) = o;
      o.x = acc[8] + bs[8];  o.y = acc[9] + bs[9];
      o.z = acc[10] + bs[10]; o.w = acc[11] + bs[11];
      *(float4*)(op + 8) = o;
      o.x = acc[12] + bs[12]; o.y = acc[13] + bs[13];
      o.z = acc[14] + bs[14]; o.w = acc[15] + bs[15];
      *(float4*)(op + 12) = o;
    }
    __syncthreads();
  }
}

extern "C" void kernel_launch(void* const* d_in, const int* in_sizes, int n_in,
                              void* d_out, int out_size, void* d_ws, size_t ws_size,
                              hipStream_t stream) {
  const float* x    = (const float*)d_in[0];
  const int*   rel  = (const int*)d_in[1];
  const float* w    = (const float*)d_in[2];
  const float* bias = (const float*)d_in[3];
  float* out = (float*)d_out;

  int* offsets = (int*)d_ws;          // 65 used, padded to 128
  int* row_idx = (int*)d_ws + 128;    // 16384

  k_pre<<<R_REL, 256, 0, stream>>>(rel, offsets, row_idx);
  k_gemm<<<dim3(NS, R_REL, 2), TPB_G, 0, stream>>>(x, w, bias, offsets, row_idx, out);
}

// Round 9
// 101.515 us; speedup vs baseline: 1.0837x; 1.0466x over previous
//
#include <hip/hip_runtime.h>

#define N_ROWS 16384
#define R_REL  64
#define IN_D   128
#define OUT_D  128
#define BM     64          // rows per tile
#define NS     4           // row-slab blocks per (relation, col-half)
#define TPB_G  256

__device__ __forceinline__ float f4c(const float4& v, int i) {
  return i == 0 ? v.x : i == 1 ? v.y : i == 2 ? v.z : v.w;
}

// ---------------------------------------------------------------------------
// k_pre (IDENTICAL to round 8 — held constant for attribution): 64 blocks,
// one per relation, no atomics; block reduce for offset + shfl-scan compact.
// ---------------------------------------------------------------------------
__global__ __launch_bounds__(256, 4) void k_pre(const int* __restrict__ rel,
                                                int* __restrict__ offsets,
                                                int* __restrict__ row_idx) {
  const int r = blockIdx.x;
  const int t = threadIdx.x;
  const int wid = t >> 6, lane = t & 63;
  __shared__ int wsum[4];
  __shared__ int sbase;
  const int4* rel4 = (const int4*)rel;

  // ---- pass 1: exclusive offset = count(rel < r) ----
  int lt = 0;
  for (int i = t; i < N_ROWS / 4; i += 256) {
    const int4 v = rel4[i];
    lt += (v.x < r) + (v.y < r) + (v.z < r) + (v.w < r);
  }
  #pragma unroll
  for (int d = 32; d >= 1; d >>= 1) lt += __shfl_down(lt, d, 64);
  if (lane == 0) wsum[wid] = lt;
  __syncthreads();
  if (t == 0) {
    const int o = wsum[0] + wsum[1] + wsum[2] + wsum[3];
    sbase = o;
    offsets[r] = o;
    if (r == R_REL - 1) offsets[R_REL] = N_ROWS;
  }
  __syncthreads();
  int base = sbase;

  // ---- pass 2: stable compact matching rows, 16 chunks x 1024 rows ----
  for (int c = 0; c < 16; ++c) {
    const int i4 = c * 256 + t;
    const int4 v = rel4[i4];
    const int m0 = (v.x == r), m1 = (v.y == r), m2 = (v.z == r), m3 = (v.w == r);
    const int cnt_t = m0 + m1 + m2 + m3;
    int incl = cnt_t;
    #pragma unroll
    for (int d = 1; d < 64; d <<= 1) {
      const int u = __shfl_up(incl, d, 64);
      if (lane >= d) incl += u;
    }
    if (lane == 63) wsum[wid] = incl;
    __syncthreads();
    int wbase = 0;
    for (int ww = 0; ww < wid; ++ww) wbase += wsum[ww];
    int pos = base + wbase + incl - cnt_t;
    const int row0 = i4 * 4;
    if (m0) row_idx[pos++] = row0;
    if (m1) row_idx[pos++] = row0 + 1;
    if (m2) row_idx[pos++] = row0 + 2;
    if (m3) row_idx[pos++] = row0 + 3;
    base += wsum[0] + wsum[1] + wsum[2] + wsum[3];
    __syncthreads();
  }
}

// ---------------------------------------------------------------------------
// k_gemm v2 (the LDS-w design, finally benched): block = (relation r,
// col-half of 64 outs, row-slab). w half (128k x 64c = 32KB) staged ONCE per
// block; x tile (64r x 128k, 32KB, XOR-swizzled) per tile. 256 thr = 16tx
// (4 cols) x 16ty (4 rows). w LDS reads are 16-unique-addr broadcasts
// (2-way bank aliasing = free), x reads conflict-free via swizzle ->
// VALU-bound by the broadcast-amplification model (~5-8 us predicted).
// LDS 64KB -> 2 blocks/CU, 8 waves/CU.
// ---------------------------------------------------------------------------
__global__ __launch_bounds__(TPB_G, 2) void k_gemm(const float* __restrict__ x,
                                                   const float* __restrict__ w,
                                                   const float* __restrict__ bias,
                                                   const int* __restrict__ offsets,
                                                   const int* __restrict__ row_idx,
                                                   float* __restrict__ out) {
  __shared__ __align__(16) float ws_[IN_D * 64];   // w[k][c], c in this half
  __shared__ __align__(16) float xs[BM * IN_D];    // swizzled 16B chunks
  const int r = blockIdx.y;
  const int c0 = blockIdx.z * 64;
  const int beg = offsets[r];
  const int cnt = offsets[r + 1] - beg;
  if (cnt == 0) return;
  const int t = threadIdx.x;
  const int tx = t & 15;
  const int ty = t >> 4;

  // ---- stage this block's w half: 2048 float4, 8 per thread, coalesced ----
  {
    const float* wr = w + (size_t)r * (IN_D * OUT_D) + c0;
    #pragma unroll
    for (int i = 0; i < 8; ++i) {
      const int id = t + i * 256;          // 0..2047
      const int k = id >> 4, c4 = id & 15;
      ((float4*)ws_)[k * 16 + c4] = *(const float4*)(wr + k * OUT_D + c4 * 4);
    }
  }

  for (int tile = blockIdx.x; tile * BM < cnt; tile += NS) {
    const int m0 = beg + tile * BM;
    const int rows = min(BM, cnt - tile * BM);

    // ---- stage x tile: 64 rows x 128 f32; thread: row=t&63, q=t>>6 ----
    {
      const int row = t & 63;
      const int q = t >> 6;                // 0..3, 8 float4 each
      if (row < rows) {
        const int g = row_idx[m0 + row];
        const float4* src = (const float4*)(x + (size_t)g * IN_D) + q * 8;
        float4* dst = (float4*)xs + row * 32;
        const int sw = row & 7;
        #pragma unroll
        for (int j = 0; j < 8; ++j) dst[(q * 8 + j) ^ sw] = src[j];
      }
    }
    __syncthreads();

    float4 acc[4];
    #pragma unroll
    for (int j = 0; j < 4; ++j) acc[j] = make_float4(0.f, 0.f, 0.f, 0.f);

    const float4* wlds = (const float4*)ws_;
    const float4* xlds = (const float4*)xs;

    #pragma unroll 4
    for (int kc = 0; kc < 32; ++kc) {
      float4 wv[4];
      #pragma unroll
      for (int kk = 0; kk < 4; ++kk) wv[kk] = wlds[(kc * 4 + kk) * 16 + tx];
      float4 xv[4];
      #pragma unroll
      for (int j = 0; j < 4; ++j) {
        const int rm = ty * 4 + j;
        xv[j] = xlds[rm * 32 + (kc ^ (rm & 7))];
      }
      #pragma unroll
      for (int kk = 0; kk < 4; ++kk) {
        #pragma unroll
        for (int j = 0; j < 4; ++j) {
          const float a = f4c(xv[j], kk);
          acc[j].x += a * wv[kk].x;
          acc[j].y += a * wv[kk].y;
          acc[j].z += a * wv[kk].z;
          acc[j].w += a * wv[kk].w;
        }
      }
    }

    // ---- epilogue ----
    const float4 bv = *(const float4*)(bias + (size_t)r * OUT_D + c0 + tx * 4);
    #pragma unroll
    for (int j = 0; j < 4; ++j) {
      const int rm = ty * 4 + j;
      if (rm < rows) {
        const int g = row_idx[m0 + rm];
        float4 o;
        o.x = acc[j].x + bv.x;
        o.y = acc[j].y + bv.y;
        o.z = acc[j].z + bv.z;
        o.w = acc[j].w + bv.w;
        *(float4*)(out + (size_t)g * OUT_D + c0 + tx * 4) = o;
      }
    }
    __syncthreads();
  }
}

extern "C" void kernel_launch(void* const* d_in, const int* in_sizes, int n_in,
                              void* d_out, int out_size, void* d_ws, size_t ws_size,
                              hipStream_t stream) {
  const float* x    = (const float*)d_in[0];
  const int*   rel  = (const int*)d_in[1];
  const float* w    = (const float*)d_in[2];
  const float* bias = (const float*)d_in[3];
  float* out = (float*)d_out;

  int* offsets = (int*)d_ws;          // 65 used, padded to 128
  int* row_idx = (int*)d_ws + 128;    // 16384

  k_pre<<<R_REL, 256, 0, stream>>>(rel, offsets, row_idx);
  k_gemm<<<dim3(NS, R_REL, 2), TPB_G, 0, stream>>>(x, w, bias, offsets, row_idx, out);
}

// Round 10
// 97.525 us; speedup vs baseline: 1.1280x; 1.0409x over previous
//
#include <hip/hip_runtime.h>

#define N_ROWS 16384
#define R_REL  64
#define IN_D   128
#define OUT_D  128
#define BM     64          // rows per tile
#define NS     4           // row-slab blocks per (relation, col-half)
#define TPB    256
#define MAXL   3968        // LDS row-list capacity (expected cnt ~256; 15.5 KB)

__device__ __forceinline__ float f4c(const float4& v, int i) {
  return i == 0 ? v.x : i == 1 ? v.y : i == 2 ? v.z : v.w;
}

// ---------------------------------------------------------------------------
// k_fused: grouping + GEMM in one dispatch. Block = (slab, relation r,
// col-half). Prologue: (1) issue w-half global->LDS loads (latency hides
// under the scan); (2) in-block scan of rel[] builds rlist = stable row list
// for relation r (identical result in every block of this r -> slabs
// partition ranks consistently). Then the v2 K-loop: x tile staged
// XOR-swizzled per 64-row slab, 4x4 register tile per thread, LDS-fed FMAs.
// LDS: w 32K + x 32K + rlist 15.5K = 81.4 KB -> 2 blocks/CU.
// ---------------------------------------------------------------------------
__global__ __launch_bounds__(TPB, 2) void k_fused(const float* __restrict__ x,
                                                  const int* __restrict__ rel,
                                                  const float* __restrict__ w,
                                                  const float* __restrict__ bias,
                                                  float* __restrict__ out) {
  __shared__ __align__(16) float ws_[IN_D * 64];   // w[k][c-half], 32 KB
  __shared__ __align__(16) float xs[BM * IN_D];    // swizzled 16B chunks, 32 KB
  __shared__ int rlist[MAXL];                      // rows of relation r
  __shared__ int wsum[4];
  const int r    = blockIdx.y;
  const int c0   = blockIdx.z * 64;
  const int slab = blockIdx.x;
  const int t    = threadIdx.x;
  const int wid  = t >> 6, lane = t & 63;
  const int tx   = t & 15, ty = t >> 4;

  // ---- (1) stage this block's w half: 2048 float4, 8/thread, coalesced ----
  {
    const float* wr = w + (size_t)r * (IN_D * OUT_D) + c0;
    #pragma unroll
    for (int i = 0; i < 8; ++i) {
      const int id = t + i * 256;          // 0..2047
      const int k = id >> 4, c4 = id & 15;
      ((float4*)ws_)[k * 16 + c4] = *(const float4*)(wr + k * OUT_D + c4 * 4);
    }
  }

  // ---- (2) in-block scan: stable-compact rows with rel==r into rlist ----
  const int4* rel4 = (const int4*)rel;
  int base = 0;                            // running rank
  for (int c = 0; c < 16; ++c) {
    const int i4 = c * 256 + t;
    const int4 v = rel4[i4];
    const int m0 = (v.x == r), m1 = (v.y == r), m2 = (v.z == r), m3 = (v.w == r);
    const int cnt_t = m0 + m1 + m2 + m3;
    int incl = cnt_t;
    #pragma unroll
    for (int d = 1; d < 64; d <<= 1) {
      const int u = __shfl_up(incl, d, 64);
      if (lane >= d) incl += u;
    }
    if (lane == 63) wsum[wid] = incl;
    __syncthreads();
    int wbase = 0;
    #pragma unroll
    for (int ww = 0; ww < 4; ++ww) if (ww < wid) wbase += wsum[ww];
    int pos = base + wbase + incl - cnt_t;
    const int row0 = i4 * 4;
    if (m0 && pos < MAXL) rlist[pos++] = row0;
    if (m1 && pos < MAXL) rlist[pos++] = row0 + 1;
    if (m2 && pos < MAXL) rlist[pos++] = row0 + 2;
    if (m3 && pos < MAXL) rlist[pos++] = row0 + 3;
    base += wsum[0] + wsum[1] + wsum[2] + wsum[3];
    __syncthreads();
  }
  const int cntR = base < MAXL ? base : MAXL;

  // ---- (3) tile loop: identical structure to v2's K-loop ----
  for (int tile = slab; tile * BM < cntR; tile += NS) {
    const int t0 = tile * BM;
    const int rows = min(BM, cntR - t0);

    // x-stage: 64 rows x 128 f32; thread: row=t&63, q=t>>6 (8 float4 each)
    {
      const int row = t & 63;
      const int q = t >> 6;
      if (row < rows) {
        const int g = rlist[t0 + row];
        const float4* src = (const float4*)(x + (size_t)g * IN_D) + q * 8;
        float4* dst = (float4*)xs + row * 32;
        const int sw = row & 7;
        #pragma unroll
        for (int j = 0; j < 8; ++j) dst[(q * 8 + j) ^ sw] = src[j];
      }
    }
    __syncthreads();

    float4 acc[4];
    #pragma unroll
    for (int j = 0; j < 4; ++j) acc[j] = make_float4(0.f, 0.f, 0.f, 0.f);

    const float4* wlds = (const float4*)ws_;
    const float4* xlds = (const float4*)xs;

    #pragma unroll 4
    for (int kc = 0; kc < 32; ++kc) {
      float4 wv[4];
      #pragma unroll
      for (int kk = 0; kk < 4; ++kk) wv[kk] = wlds[(kc * 4 + kk) * 16 + tx];
      float4 xv[4];
      #pragma unroll
      for (int j = 0; j < 4; ++j) {
        const int rm = ty * 4 + j;
        xv[j] = xlds[rm * 32 + (kc ^ (rm & 7))];
      }
      #pragma unroll
      for (int kk = 0; kk < 4; ++kk) {
        #pragma unroll
        for (int j = 0; j < 4; ++j) {
          const float a = f4c(xv[j], kk);
          acc[j].x += a * wv[kk].x;
          acc[j].y += a * wv[kk].y;
          acc[j].z += a * wv[kk].z;
          acc[j].w += a * wv[kk].w;
        }
      }
    }

    // epilogue: + bias, scatter rows back
    const float4 bv = *(const float4*)(bias + (size_t)r * OUT_D + c0 + tx * 4);
    #pragma unroll
    for (int j = 0; j < 4; ++j) {
      const int rm = ty * 4 + j;
      if (rm < rows) {
        const int g = rlist[t0 + rm];
        float4 o;
        o.x = acc[j].x + bv.x;
        o.y = acc[j].y + bv.y;
        o.z = acc[j].z + bv.z;
        o.w = acc[j].w + bv.w;
        *(float4*)(out + (size_t)g * OUT_D + c0 + tx * 4) = o;
      }
    }
    __syncthreads();
  }
}

extern "C" void kernel_launch(void* const* d_in, const int* in_sizes, int n_in,
                              void* d_out, int out_size, void* d_ws, size_t ws_size,
                              hipStream_t stream) {
  const float* x    = (const float*)d_in[0];
  const int*   rel  = (const int*)d_in[1];
  const float* w    = (const float*)d_in[2];
  const float* bias = (const float*)d_in[3];
  float* out = (float*)d_out;

  k_fused<<<dim3(NS, R_REL, 2), TPB, 0, stream>>>(x, rel, w, bias, out);
}

// Round 11
// 94.668 us; speedup vs baseline: 1.1621x; 1.0302x over previous
//
#include <hip/hip_runtime.h>

#define N_ROWS 16384
#define R_REL  64
#define IN_D   128
#define OUT_D  128
#define BM     64          // rows per tile
#define NS     4           // row-slab blocks per (relation, col-half)
#define TPB    256
#define MAXL   1024        // LDS row-list capacity (cnt ~ 256 +- 16; 4 KB)

__device__ __forceinline__ float f4c(const float4& v, int i) {
  return i == 0 ? v.x : i == 1 ? v.y : i == 2 ? v.z : v.w;
}

// ---------------------------------------------------------------------------
// k_fused v2: grouping + GEMM, one dispatch. Block = (slab, relation r,
// col-half). Phases:
//  (1) w-half global->LDS stage (loads issue first; latency hides under scan)
//  (2) SEGMENT scan (NEW): thread t owns rel[t*64 .. t*64+64). Count pass ->
//      one 256-wide block scan (6 shfl + 1 barrier) -> write pass at private
//      cursor. 2 barriers total vs 32 in the old 16-chunk scan; dependent
//      chain ~2K cyc vs ~16K.
//  (3) per-slab x tile stage (XOR-swizzled) + v2 K-loop (VALU-bound by the
//      broadcast-read model) + bias epilogue.
// LDS: w 32K + x 32K + rlist 4K = 69.7 KB -> 2 blocks/CU with headroom.
// ---------------------------------------------------------------------------
__global__ __launch_bounds__(TPB, 2) void k_fused(const float* __restrict__ x,
                                                  const int* __restrict__ rel,
                                                  const float* __restrict__ w,
                                                  const float* __restrict__ bias,
                                                  float* __restrict__ out) {
  __shared__ __align__(16) float ws_[IN_D * 64];   // w[k][c-half], 32 KB
  __shared__ __align__(16) float xs[BM * IN_D];    // swizzled 16B chunks, 32 KB
  __shared__ int rlist[MAXL];                      // rows of relation r
  __shared__ int wsum[4];
  const int r    = blockIdx.y;
  const int c0   = blockIdx.z * 64;
  const int slab = blockIdx.x;
  const int t    = threadIdx.x;
  const int wid  = t >> 6, lane = t & 63;
  const int tx   = t & 15, ty = t >> 4;

  // ---- (1) stage this block's w half: 2048 float4, 8/thread, coalesced ----
  {
    const float* wr = w + (size_t)r * (IN_D * OUT_D) + c0;
    #pragma unroll
    for (int i = 0; i < 8; ++i) {
      const int id = t + i * 256;          // 0..2047
      const int k = id >> 4, c4 = id & 15;
      ((float4*)ws_)[k * 16 + c4] = *(const float4*)(wr + k * OUT_D + c4 * 4);
    }
  }

  // ---- (2) segment scan: 64 consecutive rels per thread ----
  const int4* seg = (const int4*)rel + t * 16;
  int c_t = 0;
  #pragma unroll
  for (int i = 0; i < 16; ++i) {
    const int4 v = seg[i];
    c_t += (v.x == r) + (v.y == r) + (v.z == r) + (v.w == r);
  }
  int incl = c_t;
  #pragma unroll
  for (int d = 1; d < 64; d <<= 1) {
    const int u = __shfl_up(incl, d, 64);
    if (lane >= d) incl += u;
  }
  if (lane == 63) wsum[wid] = incl;
  __syncthreads();
  int pos = incl - c_t;                    // exclusive base within wave
  #pragma unroll
  for (int ww = 0; ww < 4; ++ww) if (ww < wid) pos += wsum[ww];
  const int cntR0 = wsum[0] + wsum[1] + wsum[2] + wsum[3];
  const int cntR = cntR0 < MAXL ? cntR0 : MAXL;
  // write pass (segments ordered by t -> stable order for free)
  #pragma unroll
  for (int i = 0; i < 16; ++i) {
    const int4 v = seg[i];
    const int row0 = t * 64 + i * 4;
    if (v.x == r && pos < MAXL) rlist[pos++] = row0;
    if (v.y == r && pos < MAXL) rlist[pos++] = row0 + 1;
    if (v.z == r && pos < MAXL) rlist[pos++] = row0 + 2;
    if (v.w == r && pos < MAXL) rlist[pos++] = row0 + 3;
  }
  __syncthreads();

  // ---- (3) tile loop: v2 K-loop structure ----
  for (int tile = slab; tile * BM < cntR; tile += NS) {
    const int t0 = tile * BM;
    const int rows = min(BM, cntR - t0);

    // x-stage: 64 rows x 128 f32; thread: row=t&63, q=t>>6 (8 float4 each)
    {
      const int row = t & 63;
      const int q = t >> 6;
      if (row < rows) {
        const int g = rlist[t0 + row];
        const float4* src = (const float4*)(x + (size_t)g * IN_D) + q * 8;
        float4* dst = (float4*)xs + row * 32;
        const int sw = row & 7;
        #pragma unroll
        for (int j = 0; j < 8; ++j) dst[(q * 8 + j) ^ sw] = src[j];
      }
    }
    __syncthreads();

    float4 acc[4];
    #pragma unroll
    for (int j = 0; j < 4; ++j) acc[j] = make_float4(0.f, 0.f, 0.f, 0.f);

    const float4* wlds = (const float4*)ws_;
    const float4* xlds = (const float4*)xs;

    #pragma unroll 4
    for (int kc = 0; kc < 32; ++kc) {
      float4 wv[4];
      #pragma unroll
      for (int kk = 0; kk < 4; ++kk) wv[kk] = wlds[(kc * 4 + kk) * 16 + tx];
      float4 xv[4];
      #pragma unroll
      for (int j = 0; j < 4; ++j) {
        const int rm = ty * 4 + j;
        xv[j] = xlds[rm * 32 + (kc ^ (rm & 7))];
      }
      #pragma unroll
      for (int kk = 0; kk < 4; ++kk) {
        #pragma unroll
        for (int j = 0; j < 4; ++j) {
          const float a = f4c(xv[j], kk);
          acc[j].x += a * wv[kk].x;
          acc[j].y += a * wv[kk].y;
          acc[j].z += a * wv[kk].z;
          acc[j].w += a * wv[kk].w;
        }
      }
    }

    // epilogue: + bias, scatter rows back
    const float4 bv = *(const float4*)(bias + (size_t)r * OUT_D + c0 + tx * 4);
    #pragma unroll
    for (int j = 0; j < 4; ++j) {
      const int rm = ty * 4 + j;
      if (rm < rows) {
        const int g = rlist[t0 + rm];
        float4 o;
        o.x = acc[j].x + bv.x;
        o.y = acc[j].y + bv.y;
        o.z = acc[j].z + bv.z;
        o.w = acc[j].w + bv.w;
        *(float4*)(out + (size_t)g * OUT_D + c0 + tx * 4) = o;
      }
    }
    __syncthreads();
  }
}

extern "C" void kernel_launch(void* const* d_in, const int* in_sizes, int n_in,
                              void* d_out, int out_size, void* d_ws, size_t ws_size,
                              hipStream_t stream) {
  const float* x    = (const float*)d_in[0];
  const int*   rel  = (const int*)d_in[1];
  const float* w    = (const float*)d_in[2];
  const float* bias = (const float*)d_in[3];
  float* out = (float*)d_out;

  k_fused<<<dim3(NS, R_REL, 2), TPB, 0, stream>>>(x, rel, w, bias, out);
}